// Round 6
// baseline (353.222 us; speedup 1.0000x reference)
//
#include <hip/hip_runtime.h>
#include <cstdint>

#define NN 8192
#define EE 131072
#define EPAD (EE + NN)   // edges + self loops = 139264
#define FIN 128
#define CH 512           // H*HID = H*OUT
#define NH 8
#define NEG 0.2f

typedef __attribute__((ext_vector_type(8))) short short8;
typedef __attribute__((ext_vector_type(4))) float f32x4;

__device__ inline unsigned short bf16rne(float x) {
    unsigned u = __float_as_uint(x);
    unsigned r = (u + 0x7FFFu + ((u >> 16) & 1u)) >> 16;
    return (unsigned short)r;
}
__device__ inline float bf16tof(unsigned short h) {
    return __uint_as_float((unsigned)h << 16);
}
__device__ inline void gload16(const void* g, void* l) {
    __builtin_amdgcn_global_load_lds((const __attribute__((address_space(1))) void*)g,
                                     (__attribute__((address_space(3))) void*)l, 16, 0, 0);
}

// ---------- CSR build ----------

__global__ __launch_bounds__(256) void k_deg(const int* __restrict__ ei, int* __restrict__ deg) {
    int e = blockIdx.x * 256 + threadIdx.x;
    if (e >= EPAD) return;
    int dst = (e < EE) ? ei[EE + e] : (e - EE);
    atomicAdd(&deg[dst], 1);
}

__global__ __launch_bounds__(1024) void k_scan(const int* __restrict__ deg, int* __restrict__ rowptr) {
    __shared__ int part[1024];
    int t = threadIdx.x;
    int loc[8];
    int s = 0;
#pragma unroll
    for (int i = 0; i < 8; i++) { loc[i] = s; s += deg[t * 8 + i]; }
    part[t] = s;
    __syncthreads();
    if (t == 0) {
        int run = 0;
        for (int i = 0; i < 1024; i++) { int tmp = part[i]; part[i] = run; run += tmp; }
        rowptr[NN] = run;
    }
    __syncthreads();
    int base = part[t];
#pragma unroll
    for (int i = 0; i < 8; i++) rowptr[t * 8 + i] = base + loc[i];
}

__global__ __launch_bounds__(256) void k_scatter(const int* __restrict__ ei, const int* __restrict__ rowptr,
                                                 int* __restrict__ cursor, int* __restrict__ ssrc) {
    int e = blockIdx.x * 256 + threadIdx.x;
    if (e >= EPAD) return;
    int src = (e < EE) ? ei[e] : (e - EE);
    int dst = (e < EE) ? ei[EE + e] : (e - EE);
    int pos = rowptr[dst] + atomicAdd(&cursor[dst], 1);
    ssrc[pos] = src;
}

// ---------- conversions ----------

__global__ __launch_bounds__(256) void k_cvt_ah(const float* __restrict__ F,
                                                unsigned short* __restrict__ Ah, int n4) {
    int i = blockIdx.x * 256 + threadIdx.x;
    if (i >= n4) return;
    f32x4 v = ((const f32x4*)F)[i];
#pragma unroll
    for (int c = 0; c < 4; c++) Ah[i * 4 + c] = bf16rne(v[c]);
}

// W[K][512] (Wl,Wr) -> Wt[n=1024][K] hi/lo (transposed, K contiguous)
template <int K>
__global__ __launch_bounds__(256) void k_cvt_w(const float* __restrict__ Wl, const float* __restrict__ Wr,
                                               unsigned short* __restrict__ Wh, unsigned short* __restrict__ Wlo) {
    int idx = blockIdx.x * 256 + threadIdx.x;   // = n*K + k
    int n = idx / K, k = idx % K;
    const float* W = (n < 512) ? Wl : Wr;
    float x = W[k * 512 + (n & 511)];
    unsigned short h = bf16rne(x);
    Wh[idx] = h;
    Wlo[idx] = bf16rne(x - bf16tof(h));
}

// ---------- split-bf16 MFMA GEMM: [8192 x K] @ [K x 1024] -> XL|XR ----------
// A in bf16-hi only; B in hi+lo (2 MFMA/frag): Ah*(Bh+Bl) ~ A_fp32 * B_fp32.

template <int K>
__global__ __launch_bounds__(256) void k_gemm_mfma(const unsigned short* __restrict__ Ah,
                                                   const unsigned short* __restrict__ Bh,
                                                   const unsigned short* __restrict__ Bl,
                                                   float* __restrict__ XL, float* __restrict__ XR) {
    __shared__ unsigned short sAh[4][128][8], sBh[4][128][8], sBl[4][128][8];
    int tid = threadIdx.x;
    int l = tid & 63;
    int w = tid >> 6, wm = w >> 1, wn = w & 1;
    int m0 = blockIdx.x * 128, n0 = blockIdx.y * 128;
    int lr = l & 15, kh = l >> 4;
    f32x4 acc[4][4] = {};

    for (int k0 = 0; k0 < K; k0 += 32) {
#pragma unroll
        for (int g = 0; g < 2; g++) {
            int cell = g * 256 + tid;
            int ckh = cell >> 7, cr = cell & 127;
            int ka = k0 + ckh * 8;
            gload16(Ah + (size_t)(m0 + cr) * K + ka, &sAh[ckh][cr][0]);
            gload16(Bh + (size_t)(n0 + cr) * K + ka, &sBh[ckh][cr][0]);
            gload16(Bl + (size_t)(n0 + cr) * K + ka, &sBl[ckh][cr][0]);
        }
        __syncthreads();
        short8 fah[4], fbh[4], fbl[4];
#pragma unroll
        for (int i = 0; i < 4; i++) {
            fah[i] = *(const short8*)&sAh[kh][wm * 64 + i * 16 + lr][0];
            fbh[i] = *(const short8*)&sBh[kh][wn * 64 + i * 16 + lr][0];
            fbl[i] = *(const short8*)&sBl[kh][wn * 64 + i * 16 + lr][0];
        }
#pragma unroll
        for (int i = 0; i < 4; i++)
#pragma unroll
            for (int j = 0; j < 4; j++) {
                acc[i][j] = __builtin_amdgcn_mfma_f32_16x16x32_bf16(fah[i], fbl[j], acc[i][j], 0, 0, 0);
                acc[i][j] = __builtin_amdgcn_mfma_f32_16x16x32_bf16(fah[i], fbh[j], acc[i][j], 0, 0, 0);
            }
        __syncthreads();
    }
    // C/D layout: col = lane&15, row = (lane>>4)*4 + q  [m89-verified]
    int colt = n0 + wn * 64;
    float* O = (colt < 512) ? XL : XR;
    int cb = colt & 511;
#pragma unroll
    for (int i = 0; i < 4; i++) {
        int mg = m0 + wm * 64 + i * 16 + kh * 4;
#pragma unroll
        for (int j = 0; j < 4; j++) {
            int cg = cb + j * 16 + lr;
#pragma unroll
            for (int q = 0; q < 4; q++)
                O[(size_t)(mg + q) * CH + cg] = acc[i][j][q];
        }
    }
}

// ---------- fused per-node: logits + online softmax + aggregation ----------
// Block = one node; 4 waves = (head-group g in {0,1}) x (edge-half hf in {0,1}).
// Each wave: online softmax over its half of the edge list (2-edge chunks,
// double-buffered, 6-level joint fold). Halves merged via LDS at the end:
// m* = max(m1,m2); s* = s1*e^{m1-m*} + s2*e^{m2-m*}; acc rescaled likewise.
// Tail edges masked via logit=-1e30 (p=0).

#define LDCHUNK(cb, CS, CX)                                                    \
  {                                                                            \
    CS[0] = ssrc[(cb)];                                                        \
    CS[1] = ssrc[((cb) + 1 < endw) ? (cb) + 1 : begw];                         \
    _Pragma("unroll") for (int e = 0; e < 2; e++) {                            \
      const float* _p = XLg + (size_t)CS[e] * CH;                              \
      _Pragma("unroll") for (int r = 0; r < 4; r++) CX[e][r] = _p[r * 64];     \
    }                                                                          \
  }

#define PROCESS(CX, cb)                                                        \
  {                                                                            \
    float v[2][4];                                                             \
    _Pragma("unroll") for (int e = 0; e < 2; e++)                              \
      _Pragma("unroll") for (int r = 0; r < 4; r++) {                          \
        float t = CX[e][r] + xr[r];                                            \
        t = (t > 0.f) ? t : NEG * t;                                           \
        v[e][r] = t * at[r];                                                   \
      }                                                                        \
    {                                                                          \
      int b = l & 1;                                                           \
      _Pragma("unroll") for (int e = 0; e < 2; e++) {                          \
        float k0 = b ? v[e][1] : v[e][0], s0 = b ? v[e][0] : v[e][1];          \
        float k1 = b ? v[e][3] : v[e][2], s1 = b ? v[e][2] : v[e][3];          \
        v[e][0] = k0 + __shfl_xor(s0, 1);                                      \
        v[e][1] = k1 + __shfl_xor(s1, 1);                                      \
      }                                                                        \
    }                                                                          \
    {                                                                          \
      int b = (l >> 1) & 1;                                                    \
      _Pragma("unroll") for (int e = 0; e < 2; e++) {                          \
        float k0 = b ? v[e][1] : v[e][0], s0 = b ? v[e][0] : v[e][1];          \
        v[e][0] = k0 + __shfl_xor(s0, 2);                                      \
      }                                                                        \
    }                                                                          \
    float z;                                                                   \
    {                                                                          \
      int b = (l >> 2) & 1;                                                    \
      z = (b ? v[1][0] : v[0][0]) + __shfl_xor(b ? v[0][0] : v[1][0], 4);      \
    }                                                                          \
    z += __shfl_xor(z, 8);                                                     \
    z += __shfl_xor(z, 16);                                                    \
    z += __shfl_xor(z, 32);                                                    \
    if ((cb) + ((l >> 2) & 1) >= endw) z = -1e30f;                             \
    float mc = fmaxf(z, __shfl_xor(z, 4));                                     \
    unsigned long long grow = __ballot(mc > mh);                               \
    if (grow == 0ULL) {                                                        \
      float p = __expf(z - mh);                                                \
      float q = p + __shfl_xor(p, 4);                                          \
      sh += q;                                                                 \
      _Pragma("unroll") for (int r = 0; r < 4; r++)                            \
        acc[r] += __shfl(p, r) * CX[0][r] + __shfl(p, 4 + r) * CX[1][r];       \
    } else {                                                                   \
      float nm = fmaxf(mh, mc);                                                \
      float scale = __expf(mh - nm);                                           \
      float p = __expf(z - nm);                                                \
      float q = p + __shfl_xor(p, 4);                                          \
      sh = sh * scale + q;                                                     \
      mh = nm;                                                                 \
      _Pragma("unroll") for (int r = 0; r < 4; r++)                            \
        acc[r] = acc[r] * __shfl(scale, r) +                                   \
                 __shfl(p, r) * CX[0][r] + __shfl(p, 4 + r) * CX[1][r];        \
    }                                                                          \
  }

template <int WRITE_BF16>
__global__ __launch_bounds__(256) void k_node2(const float* __restrict__ XL,
                                               const float* __restrict__ XR,
                                               const int* __restrict__ rowptr,
                                               const int* __restrict__ ssrc,
                                               const float* __restrict__ att,
                                               const float* __restrict__ bias,
                                               float* __restrict__ OUT,
                                               unsigned short* __restrict__ OAh) {
    int w = threadIdx.x >> 6;
    int g = w >> 1, hf = w & 1;          // head-group, edge-half
    int n = blockIdx.x;
    int l = threadIdx.x & 63;
    int beg = rowptr[n], end = rowptr[n + 1];
    int mid = beg + ((end - beg + 1) >> 1);
    int begw = hf ? mid : beg;
    int endw = hf ? end : mid;
    int hb = g * 256 + l;                // channel base within row

    const float* XLg = XL + hb;
    float xr[4], at[4], acc[4];
    const float* pr = XR + (size_t)n * CH + hb;
#pragma unroll
    for (int r = 0; r < 4; r++) {
        xr[r] = pr[r * 64];
        at[r] = att[hb + r * 64];
        acc[r] = 0.f;
    }
    float mh = -1e30f, sh = 0.f;

    if (begw < endw) {
        int srcA[2], srcB[2];
        float curA[2][4], curB[2][4];
        LDCHUNK(begw, srcA, curA);
        int base = begw;
        while (true) {
            if (base + 2 < endw) LDCHUNK(base + 2, srcB, curB);
            PROCESS(curA, base);
            base += 2;
            if (base >= endw) break;
            if (base + 2 < endw) LDCHUNK(base + 2, srcA, curA);
            PROCESS(curB, base);
            base += 2;
            if (base >= endw) break;
        }
    }

    // merge the two edge-halves (per head-group) via LDS
    __shared__ float smA[4][4][64];
    __shared__ float smM[4][64];
    __shared__ float smS[4][64];
#pragma unroll
    for (int r = 0; r < 4; r++) smA[w][r][l] = acc[r];
    smM[w][l] = mh;
    smS[w][l] = sh;
    __syncthreads();
    if (hf == 0) {
        int pw = w | 1;
        float m2 = smM[pw][l], s2 = smS[pw][l];
        float nm = fmaxf(mh, m2);
        float a1 = __expf(mh - nm), a2 = __expf(m2 - nm);
        float s = sh * a1 + s2 * a2;
        float inv = 1.f / s;
        size_t obase = (size_t)n * CH + hb;
#pragma unroll
        for (int r = 0; r < 4; r++) {
            float av = acc[r] * __shfl(a1, r) + smA[pw][r][l] * __shfl(a2, r);
            float wv = av * __shfl(inv, r) + bias[hb + r * 64];
            if (WRITE_BF16) {
                OAh[obase + r * 64] = bf16rne(wv);
            } else {
                wv = (wv > 0.f) ? wv : (__expf(wv) - 1.f);
                OUT[obase + r * 64] = wv;
            }
        }
    }
}

// ---------- host ----------

extern "C" void kernel_launch(void* const* d_in, const int* in_sizes, int n_in,
                              void* d_out, int out_size, void* d_ws, size_t ws_size,
                              hipStream_t stream) {
    const float* x    = (const float*)d_in[0];
    const int*   ei   = (const int*)d_in[1];
    const float* W1l  = (const float*)d_in[2];
    const float* W1r  = (const float*)d_in[3];
    const float* att1 = (const float*)d_in[4];
    const float* b1   = (const float*)d_in[5];
    const float* W2l  = (const float*)d_in[6];
    const float* W2r  = (const float*)d_in[7];
    const float* att2 = (const float*)d_in[8];
    const float* b2   = (const float*)d_in[9];
    float* out = (float*)d_out;

    char* ws = (char*)d_ws;
    int* rowptr = (int*)ws;                 // NN+1
    int* cursor = rowptr + NN + 1;          // NN
    int* deg    = cursor + NN;              // NN
    int* ssrc   = deg + NN;                 // EPAD
    float* XL = (float*)(((uintptr_t)(ssrc + EPAD) + 255) & ~(uintptr_t)255);
    float* XR = XL + (size_t)NN * CH;
    unsigned short* A_h = (unsigned short*)(XR + (size_t)NN * CH);  // NN*CH bf16
    unsigned short* W1h = A_h + (size_t)NN * CH;   // 1024*FIN
    unsigned short* W1o = W1h + 1024 * FIN;
    unsigned short* W2h = W1o + 1024 * FIN;        // 1024*CH
    unsigned short* W2o = W2h + 1024 * CH;

    hipMemsetAsync(cursor, 0, (size_t)2 * NN * sizeof(int), stream);
    k_deg<<<(EPAD + 255) / 256, 256, 0, stream>>>(ei, deg);
    k_scan<<<1, 1024, 0, stream>>>(deg, rowptr);
    k_scatter<<<(EPAD + 255) / 256, 256, 0, stream>>>(ei, rowptr, cursor, ssrc);
    k_cvt_w<FIN><<<1024 * FIN / 256, 256, 0, stream>>>(W1l, W1r, W1h, W1o);
    k_cvt_w<CH><<<1024 * CH / 256, 256, 0, stream>>>(W2l, W2r, W2h, W2o);

    for (int b = 0; b < 2; b++) {
        const float* f = x + (size_t)b * NN * FIN;
        k_cvt_ah<<<NN * FIN / 4 / 256, 256, 0, stream>>>(f, A_h, NN * FIN / 4);
        k_gemm_mfma<FIN><<<dim3(NN / 128, 8), 256, 0, stream>>>(A_h, W1h, W1o, XL, XR);
        k_node2<1><<<NN, 256, 0, stream>>>(XL, XR, rowptr, ssrc, att1, b1, nullptr, A_h);
        k_gemm_mfma<CH><<<dim3(NN / 128, 8), 256, 0, stream>>>(A_h, W2h, W2o, XL, XR);
        k_node2<0><<<NN, 256, 0, stream>>>(XL, XR, rowptr, ssrc, att2, b2,
                                           out + (size_t)b * NN * CH, nullptr);
    }
}

// Round 7
// 324.949 us; speedup vs baseline: 1.0870x; 1.0870x over previous
//
#include <hip/hip_runtime.h>
#include <cstdint>

#define NN 8192
#define EE 131072
#define EPAD (EE + NN)   // edges + self loops = 139264
#define FIN 128
#define CH 512           // H*HID = H*OUT
#define NH 8
#define NEG 0.2f

typedef __attribute__((ext_vector_type(8))) short short8;
typedef __attribute__((ext_vector_type(4))) float f32x4;

__device__ inline unsigned short bf16rne(float x) {
    unsigned u = __float_as_uint(x);
    unsigned r = (u + 0x7FFFu + ((u >> 16) & 1u)) >> 16;
    return (unsigned short)r;
}
__device__ inline float bf16tof(unsigned short h) {
    return __uint_as_float((unsigned)h << 16);
}
__device__ inline void gload16(const void* g, void* l) {
    __builtin_amdgcn_global_load_lds((const __attribute__((address_space(1))) void*)g,
                                     (__attribute__((address_space(3))) void*)l, 16, 0, 0);
}
// broadcast lane's float via v_readlane (VALU, no DS-crossbar traffic)
#define RLF(x, lane) __int_as_float(__builtin_amdgcn_readlane(__float_as_int(x), (lane)))

// ---------- CSR build ----------

__global__ __launch_bounds__(256) void k_deg(const int* __restrict__ ei, int* __restrict__ deg) {
    int e = blockIdx.x * 256 + threadIdx.x;
    if (e >= EPAD) return;
    int dst = (e < EE) ? ei[EE + e] : (e - EE);
    atomicAdd(&deg[dst], 1);
}

__global__ __launch_bounds__(1024) void k_scan(const int* __restrict__ deg, int* __restrict__ rowptr) {
    __shared__ int part[1024];
    int t = threadIdx.x;
    int loc[8];
    int s = 0;
#pragma unroll
    for (int i = 0; i < 8; i++) { loc[i] = s; s += deg[t * 8 + i]; }
    part[t] = s;
    __syncthreads();
    if (t == 0) {
        int run = 0;
        for (int i = 0; i < 1024; i++) { int tmp = part[i]; part[i] = run; run += tmp; }
        rowptr[NN] = run;
    }
    __syncthreads();
    int base = part[t];
#pragma unroll
    for (int i = 0; i < 8; i++) rowptr[t * 8 + i] = base + loc[i];
}

__global__ __launch_bounds__(256) void k_scatter(const int* __restrict__ ei, const int* __restrict__ rowptr,
                                                 int* __restrict__ cursor, int* __restrict__ ssrc) {
    int e = blockIdx.x * 256 + threadIdx.x;
    if (e >= EPAD) return;
    int src = (e < EE) ? ei[e] : (e - EE);
    int dst = (e < EE) ? ei[EE + e] : (e - EE);
    int pos = rowptr[dst] + atomicAdd(&cursor[dst], 1);
    ssrc[pos] = src;
}

// ---------- conversions ----------

__global__ __launch_bounds__(256) void k_cvt_ah(const float* __restrict__ F,
                                                unsigned short* __restrict__ Ah, int n4) {
    int i = blockIdx.x * 256 + threadIdx.x;
    if (i >= n4) return;
    f32x4 v = ((const f32x4*)F)[i];
#pragma unroll
    for (int c = 0; c < 4; c++) Ah[i * 4 + c] = bf16rne(v[c]);
}

// W[K][512] (Wl,Wr) -> Wt[n=1024][K] hi/lo (transposed, K contiguous)
template <int K>
__global__ __launch_bounds__(256) void k_cvt_w(const float* __restrict__ Wl, const float* __restrict__ Wr,
                                               unsigned short* __restrict__ Wh, unsigned short* __restrict__ Wlo) {
    int idx = blockIdx.x * 256 + threadIdx.x;   // = n*K + k
    int n = idx / K, k = idx % K;
    const float* W = (n < 512) ? Wl : Wr;
    float x = W[k * 512 + (n & 511)];
    unsigned short h = bf16rne(x);
    Wh[idx] = h;
    Wlo[idx] = bf16rne(x - bf16tof(h));
}

// ---------- split-bf16 MFMA GEMM: [8192 x K] @ [K x 1024] -> XL|XR ----------
// A in bf16-hi only; B in hi+lo (2 MFMA/frag): Ah*(Bh+Bl) ~ A_fp32 * B_fp32.

template <int K>
__global__ __launch_bounds__(256) void k_gemm_mfma(const unsigned short* __restrict__ Ah,
                                                   const unsigned short* __restrict__ Bh,
                                                   const unsigned short* __restrict__ Bl,
                                                   float* __restrict__ XL, float* __restrict__ XR) {
    __shared__ unsigned short sAh[4][128][8], sBh[4][128][8], sBl[4][128][8];
    int tid = threadIdx.x;
    int l = tid & 63;
    int w = tid >> 6, wm = w >> 1, wn = w & 1;
    int m0 = blockIdx.x * 128, n0 = blockIdx.y * 128;
    int lr = l & 15, kh = l >> 4;
    f32x4 acc[4][4] = {};

    for (int k0 = 0; k0 < K; k0 += 32) {
#pragma unroll
        for (int g = 0; g < 2; g++) {
            int cell = g * 256 + tid;
            int ckh = cell >> 7, cr = cell & 127;
            int ka = k0 + ckh * 8;
            gload16(Ah + (size_t)(m0 + cr) * K + ka, &sAh[ckh][cr][0]);
            gload16(Bh + (size_t)(n0 + cr) * K + ka, &sBh[ckh][cr][0]);
            gload16(Bl + (size_t)(n0 + cr) * K + ka, &sBl[ckh][cr][0]);
        }
        __syncthreads();
        short8 fah[4], fbh[4], fbl[4];
#pragma unroll
        for (int i = 0; i < 4; i++) {
            fah[i] = *(const short8*)&sAh[kh][wm * 64 + i * 16 + lr][0];
            fbh[i] = *(const short8*)&sBh[kh][wn * 64 + i * 16 + lr][0];
            fbl[i] = *(const short8*)&sBl[kh][wn * 64 + i * 16 + lr][0];
        }
#pragma unroll
        for (int i = 0; i < 4; i++)
#pragma unroll
            for (int j = 0; j < 4; j++) {
                acc[i][j] = __builtin_amdgcn_mfma_f32_16x16x32_bf16(fah[i], fbl[j], acc[i][j], 0, 0, 0);
                acc[i][j] = __builtin_amdgcn_mfma_f32_16x16x32_bf16(fah[i], fbh[j], acc[i][j], 0, 0, 0);
            }
        __syncthreads();
    }
    // C/D layout: col = lane&15, row = (lane>>4)*4 + q  [m89-verified]
    int colt = n0 + wn * 64;
    float* O = (colt < 512) ? XL : XR;
    int cb = colt & 511;
#pragma unroll
    for (int i = 0; i < 4; i++) {
        int mg = m0 + wm * 64 + i * 16 + kh * 4;
#pragma unroll
        for (int j = 0; j < 4; j++) {
            int cg = cb + j * 16 + lr;
#pragma unroll
            for (int q = 0; q < 4; q++)
                O[(size_t)(mg + q) * CH + cg] = acc[i][j][q];
        }
    }
}

// ---------- fused per-node: logits + online softmax + aggregation ----------
// 2 waves per node (head-group g in {0,1}, 4 heads each). 4-edge chunks,
// double-buffered. Joint fold of 16 (edge,head) regs: lane bits 1:0 <- head,
// bits 3:2 <- edge (17 DS ops / 4 edges); p broadcasts via v_readlane (0 DS).
// Tail edges masked via logit=-1e30 (p=0).

#define LDCHUNK(cb, CS, CX)                                                    \
  {                                                                            \
    CS[0] = ssrc[(cb)];                                                        \
    CS[1] = ssrc[((cb) + 1 < end) ? (cb) + 1 : beg];                           \
    CS[2] = ssrc[((cb) + 2 < end) ? (cb) + 2 : beg];                           \
    CS[3] = ssrc[((cb) + 3 < end) ? (cb) + 3 : beg];                           \
    _Pragma("unroll") for (int e = 0; e < 4; e++) {                            \
      const float* _p = XLg + (size_t)CS[e] * CH;                              \
      _Pragma("unroll") for (int r = 0; r < 4; r++) CX[e][r] = _p[r * 64];     \
    }                                                                          \
  }

#define PROCESS(CX, cb)                                                        \
  {                                                                            \
    float v[4][4];                                                             \
    _Pragma("unroll") for (int e = 0; e < 4; e++)                              \
      _Pragma("unroll") for (int r = 0; r < 4; r++) {                          \
        float t = CX[e][r] + xr[r];                                            \
        t = (t > 0.f) ? t : NEG * t;                                           \
        v[e][r] = t * at[r];                                                   \
      }                                                                        \
    {                                                                          \
      int b = l & 1; /* head bit0 */                                           \
      _Pragma("unroll") for (int e = 0; e < 4; e++) {                          \
        float k0 = b ? v[e][1] : v[e][0], s0 = b ? v[e][0] : v[e][1];          \
        float k1 = b ? v[e][3] : v[e][2], s1 = b ? v[e][2] : v[e][3];          \
        v[e][0] = k0 + __shfl_xor(s0, 1);                                      \
        v[e][1] = k1 + __shfl_xor(s1, 1);                                      \
      }                                                                        \
    }                                                                          \
    {                                                                          \
      int b = (l >> 1) & 1; /* head bit1 */                                    \
      _Pragma("unroll") for (int e = 0; e < 4; e++) {                          \
        float k0 = b ? v[e][1] : v[e][0], s0 = b ? v[e][0] : v[e][1];          \
        v[e][0] = k0 + __shfl_xor(s0, 2);                                      \
      }                                                                        \
    }                                                                          \
    {                                                                          \
      int b = (l >> 2) & 1; /* edge bit0 */                                    \
      float k0 = b ? v[1][0] : v[0][0], s0 = b ? v[0][0] : v[1][0];            \
      float k1 = b ? v[3][0] : v[2][0], s1 = b ? v[2][0] : v[3][0];            \
      v[0][0] = k0 + __shfl_xor(s0, 4);                                        \
      v[1][0] = k1 + __shfl_xor(s1, 4);                                        \
    }                                                                          \
    float z;                                                                   \
    {                                                                          \
      int b = (l >> 3) & 1; /* edge bit1 */                                    \
      float k0 = b ? v[1][0] : v[0][0], s0 = b ? v[0][0] : v[1][0];            \
      z = k0 + __shfl_xor(s0, 8);                                              \
    }                                                                          \
    z += __shfl_xor(z, 16);                                                    \
    z += __shfl_xor(z, 32);                                                    \
    if ((cb) + ((l >> 2) & 3) >= end) z = -1e30f;                              \
    float mc = fmaxf(z, __shfl_xor(z, 4));                                     \
    mc = fmaxf(mc, __shfl_xor(mc, 8));                                         \
    unsigned long long grow = __ballot(mc > mh);                               \
    if (grow == 0ULL) {                                                        \
      float p = __expf(z - mh);                                                \
      float q = p + __shfl_xor(p, 4);                                          \
      q += __shfl_xor(q, 8);                                                   \
      sh += q;                                                                 \
      _Pragma("unroll") for (int r = 0; r < 4; r++) {                          \
        float a2 = acc[r];                                                     \
        a2 += RLF(p, r) * CX[0][r];                                            \
        a2 += RLF(p, 4 + r) * CX[1][r];                                        \
        a2 += RLF(p, 8 + r) * CX[2][r];                                        \
        a2 += RLF(p, 12 + r) * CX[3][r];                                       \
        acc[r] = a2;                                                           \
      }                                                                        \
    } else {                                                                   \
      float nm = fmaxf(mh, mc);                                                \
      float scale = __expf(mh - nm);                                           \
      float p = __expf(z - nm);                                                \
      float q = p + __shfl_xor(p, 4);                                          \
      q += __shfl_xor(q, 8);                                                   \
      sh = sh * scale + q;                                                     \
      mh = nm;                                                                 \
      _Pragma("unroll") for (int r = 0; r < 4; r++) {                          \
        float a2 = acc[r] * RLF(scale, r);                                     \
        a2 += RLF(p, r) * CX[0][r];                                            \
        a2 += RLF(p, 4 + r) * CX[1][r];                                        \
        a2 += RLF(p, 8 + r) * CX[2][r];                                        \
        a2 += RLF(p, 12 + r) * CX[3][r];                                       \
        acc[r] = a2;                                                           \
      }                                                                        \
    }                                                                          \
  }

template <int WRITE_BF16>
__global__ __launch_bounds__(256) void k_node2(const float* __restrict__ XL,
                                               const float* __restrict__ XR,
                                               const int* __restrict__ rowptr,
                                               const int* __restrict__ ssrc,
                                               const float* __restrict__ att,
                                               const float* __restrict__ bias,
                                               float* __restrict__ OUT,
                                               unsigned short* __restrict__ OAh) {
    int w = threadIdx.x >> 6;
    int n = blockIdx.x * 2 + (w >> 1);
    int g = w & 1;                       // head-group: heads g*4 .. g*4+3
    int l = threadIdx.x & 63;
    int beg = rowptr[n], end = rowptr[n + 1];
    int hb = g * 256 + l;                // channel base within row

    const float* XLg = XL + hb;
    float xr[4], at[4], acc[4];
    const float* pr = XR + (size_t)n * CH + hb;
#pragma unroll
    for (int r = 0; r < 4; r++) {
        xr[r] = pr[r * 64];
        at[r] = att[hb + r * 64];
        acc[r] = 0.f;
    }
    float mh = -1e30f, sh = 0.f;

    int srcA[4], srcB[4];
    float curA[4][4], curB[4][4];
    LDCHUNK(beg, srcA, curA);
    int base = beg;
    while (true) {
        if (base + 4 < end) LDCHUNK(base + 4, srcB, curB);
        PROCESS(curA, base);
        base += 4;
        if (base >= end) break;
        if (base + 4 < end) LDCHUNK(base + 4, srcA, curA);
        PROCESS(curB, base);
        base += 4;
        if (base >= end) break;
    }

    float inv = 1.f / sh;
    size_t obase = (size_t)n * CH + hb;
#pragma unroll
    for (int r = 0; r < 4; r++) {
        float wv = acc[r] * RLF(inv, r) + bias[hb + r * 64];
        if (WRITE_BF16) {
            OAh[obase + r * 64] = bf16rne(wv);
        } else {
            wv = (wv > 0.f) ? wv : (__expf(wv) - 1.f);
            OUT[obase + r * 64] = wv;
        }
    }
}

// ---------- host ----------

extern "C" void kernel_launch(void* const* d_in, const int* in_sizes, int n_in,
                              void* d_out, int out_size, void* d_ws, size_t ws_size,
                              hipStream_t stream) {
    const float* x    = (const float*)d_in[0];
    const int*   ei   = (const int*)d_in[1];
    const float* W1l  = (const float*)d_in[2];
    const float* W1r  = (const float*)d_in[3];
    const float* att1 = (const float*)d_in[4];
    const float* b1   = (const float*)d_in[5];
    const float* W2l  = (const float*)d_in[6];
    const float* W2r  = (const float*)d_in[7];
    const float* att2 = (const float*)d_in[8];
    const float* b2   = (const float*)d_in[9];
    float* out = (float*)d_out;

    char* ws = (char*)d_ws;
    int* rowptr = (int*)ws;                 // NN+1
    int* cursor = rowptr + NN + 1;          // NN
    int* deg    = cursor + NN;              // NN
    int* ssrc   = deg + NN;                 // EPAD
    float* XL = (float*)(((uintptr_t)(ssrc + EPAD) + 255) & ~(uintptr_t)255);
    float* XR = XL + (size_t)NN * CH;
    unsigned short* A_h = (unsigned short*)(XR + (size_t)NN * CH);  // NN*CH bf16
    unsigned short* W1h = A_h + (size_t)NN * CH;   // 1024*FIN
    unsigned short* W1o = W1h + 1024 * FIN;
    unsigned short* W2h = W1o + 1024 * FIN;        // 1024*CH
    unsigned short* W2o = W2h + 1024 * CH;

    hipMemsetAsync(cursor, 0, (size_t)2 * NN * sizeof(int), stream);
    k_deg<<<(EPAD + 255) / 256, 256, 0, stream>>>(ei, deg);
    k_scan<<<1, 1024, 0, stream>>>(deg, rowptr);
    k_scatter<<<(EPAD + 255) / 256, 256, 0, stream>>>(ei, rowptr, cursor, ssrc);
    k_cvt_w<FIN><<<1024 * FIN / 256, 256, 0, stream>>>(W1l, W1r, W1h, W1o);
    k_cvt_w<CH><<<1024 * CH / 256, 256, 0, stream>>>(W2l, W2r, W2h, W2o);

    for (int b = 0; b < 2; b++) {
        const float* f = x + (size_t)b * NN * FIN;
        k_cvt_ah<<<NN * FIN / 4 / 256, 256, 0, stream>>>(f, A_h, NN * FIN / 4);
        k_gemm_mfma<FIN><<<dim3(NN / 128, 8), 256, 0, stream>>>(A_h, W1h, W1o, XL, XR);
        k_node2<1><<<NN / 2, 256, 0, stream>>>(XL, XR, rowptr, ssrc, att1, b1, nullptr, A_h);
        k_gemm_mfma<CH><<<dim3(NN / 128, 8), 256, 0, stream>>>(A_h, W2h, W2o, XL, XR);
        k_node2<0><<<NN / 2, 256, 0, stream>>>(XL, XR, rowptr, ssrc, att2, b2,
                                               out + (size_t)b * NN * CH, nullptr);
    }
}